// Round 1
// baseline (779.813 us; speedup 1.0000x reference)
//
#include <hip/hip_runtime.h>
#include <hip/hip_bf16.h>

#define BB 16
#define TT 2048
#define DD 384
#define NBB 128
#define EPSF 1e-8f

// ---------- helpers for templated h_seq storage ----------
__device__ inline float ht2f(float x) { return x; }
__device__ inline float ht2f(__hip_bfloat16 x) { return __bfloat162float(x); }
__device__ inline void f2ht(float* p, float x) { *p = x; }
__device__ inline void f2ht(__hip_bfloat16* p, float x) { *p = __float2bfloat16(x); }

// ---------- kernel 1: combined weights Wc[m][k][j] = sum_d W_in[k][d]*Wm[d][j] ----------
// m: 0=biv, 1=dec, 2=inj.  Wc layout: [3][4][DD] row-major.
__global__ void precompute_wc(const float* __restrict__ W_in,
                              const float* __restrict__ W_biv,
                              const float* __restrict__ W_dec,
                              const float* __restrict__ W_inj,
                              float* __restrict__ Wc) {
    int idx = blockIdx.x * blockDim.x + threadIdx.x;  // 0 .. 3*DD-1
    if (idx >= 3 * DD) return;
    int m = idx / DD, j = idx - m * DD;
    const float* __restrict__ W = (m == 0) ? W_biv : (m == 1) ? W_dec : W_inj;
    float a0 = 0.f, a1 = 0.f, a2 = 0.f, a3 = 0.f;
    for (int d = 0; d < DD; ++d) {
        float wv = W[d * DD + j];          // coalesced across lanes (j contiguous)
        a0 = fmaf(W_in[0 * DD + d], wv, a0);
        a1 = fmaf(W_in[1 * DD + d], wv, a1);
        a2 = fmaf(W_in[2 * DD + d], wv, a2);
        a3 = fmaf(W_in[3 * DD + d], wv, a3);
    }
    float* o = Wc + (size_t)m * 4 * DD + j;
    o[0 * DD] = a0; o[1 * DD] = a1; o[2 * DD] = a2; o[3 * DD] = a3;
}

// ---------- kernel 2: sequential scan, one thread per (batch, block) chain ----------
// grid 32 x 64: blockIdx -> (b, half), lane -> chain n = half*64+lane
template <typename HT>
__global__ __launch_bounds__(64) void scan_kernel(
        const float* __restrict__ quat,   // [BB][TT][4]
        const float* __restrict__ Wc,     // [3][4][DD]
        const float* __restrict__ b_biv,
        const float* __restrict__ b_dec,
        const float* __restrict__ b_inj,
        HT* __restrict__ h_seq) {         // [BB][TT][DD]
    int b = blockIdx.x >> 1;
    int n = ((blockIdx.x & 1) << 6) + threadIdx.x;  // 0..127
    int j0 = 3 * n;

    const float* __restrict__ Wb = Wc;
    const float* __restrict__ Wd = Wc + 4 * DD;
    const float* __restrict__ Wi = Wc + 8 * DD;
    float wb[4][3], wd[4][3], wi[4][3];
#pragma unroll
    for (int k = 0; k < 4; ++k)
#pragma unroll
        for (int c = 0; c < 3; ++c) {
            wb[k][c] = Wb[k * DD + j0 + c];
            wd[k][c] = Wd[k * DD + j0 + c];
            wi[k][c] = Wi[k * DD + j0 + c];
        }
    float bbv[3], bdv[3], biv[3];
#pragma unroll
    for (int c = 0; c < 3; ++c) {
        bbv[c] = b_biv[j0 + c];
        bdv[c] = b_dec[j0 + c];
        biv[c] = b_inj[j0 + c];
    }

    const float4* __restrict__ qp4 = (const float4*)(quat + (size_t)b * TT * 4);
    HT* __restrict__ hp = h_seq + (size_t)b * TT * DD + j0;

    float vx = 0.f, vy = 0.f, vz = 0.f;

#define DOT4(W, c, bias) \
    fmaf(q.w, W[3][c], fmaf(q.z, W[2][c], fmaf(q.y, W[1][c], fmaf(q.x, W[0][c], bias))))

    for (int t = 0; t < TT; ++t) {
        float4 q = qp4[t];
        // bivector for this block (3 comps), decay (3), injection (3)
        float bx = DOT4(wb, 0, bbv[0]);
        float by = DOT4(wb, 1, bbv[1]);
        float bz = DOT4(wb, 2, bbv[2]);
        float d0 = DOT4(wd, 0, bdv[0]);
        float d1 = DOT4(wd, 1, bdv[1]);
        float d2 = DOT4(wd, 2, bdv[2]);
        float i0 = DOT4(wi, 0, biv[0]);
        float i1 = DOT4(wi, 1, biv[1]);
        float i2 = DOT4(wi, 2, biv[2]);

        float dec0 = 1.f / (1.f + __expf(-d0));
        float dec1 = 1.f / (1.f + __expf(-d1));
        float dec2 = 1.f / (1.f + __expf(-d2));

        float nb = fmaxf(sqrtf(fmaf(bx, bx, fmaf(by, by, bz * bz))), EPSF);
        float half = 0.5f * nb;
        float w = __cosf(half);
        float s = __sinf(half) / nb;
        float qx = s * bz, qy = -s * by, qz = s * bx;

        // rotation (depends on v - the serial chain)
        float tx = 2.f * (qy * vz - qz * vy);
        float ty = 2.f * (qz * vx - qx * vz);
        float tz = 2.f * (qx * vy - qy * vx);
        float rx = vx + w * tx + (qy * tz - qz * ty);
        float ry = vy + w * ty + (qz * tx - qx * tz);
        float rz = vz + w * tz + (qx * ty - qy * tx);

        vx = fmaf(dec0, rx, i0);
        vy = fmaf(dec1, ry, i1);
        vz = fmaf(dec2, rz, i2);

        HT* o = hp + (size_t)t * DD;
        f2ht(o + 0, vx);
        f2ht(o + 1, vy);
        f2ht(o + 2, vz);
    }
#undef DOT4
}

// ---------- kernel 3: out = normalize(h_seq @ W_out), one wave per (b,t) row ----------
template <typename HT>
__global__ __launch_bounds__(256) void out_kernel(
        const HT* __restrict__ h_seq,    // [BB*TT][DD]
        const float* __restrict__ W_out, // [DD][4]
        float* __restrict__ out) {       // [BB*TT][4]
    int row = blockIdx.x * 4 + (threadIdx.x >> 6);
    int lane = threadIdx.x & 63;
    const HT* __restrict__ h = h_seq + (size_t)row * DD;
    float a0 = 0.f, a1 = 0.f, a2 = 0.f, a3 = 0.f;
#pragma unroll
    for (int d = lane; d < DD; d += 64) {
        float hv = ht2f(h[d]);
        float4 w = *(const float4*)(W_out + d * 4);
        a0 = fmaf(hv, w.x, a0);
        a1 = fmaf(hv, w.y, a1);
        a2 = fmaf(hv, w.z, a2);
        a3 = fmaf(hv, w.w, a3);
    }
#pragma unroll
    for (int off = 32; off; off >>= 1) {
        a0 += __shfl_xor(a0, off);
        a1 += __shfl_xor(a1, off);
        a2 += __shfl_xor(a2, off);
        a3 += __shfl_xor(a3, off);
    }
    if (lane == 0) {
        float norm = fmaxf(sqrtf(fmaf(a0, a0, fmaf(a1, a1, fmaf(a2, a2, a3 * a3)))), EPSF);
        float inv = 1.f / norm;
        float4 o = {a0 * inv, a1 * inv, a2 * inv, a3 * inv};
        *(float4*)(out + (size_t)row * 4) = o;
    }
}

extern "C" void kernel_launch(void* const* d_in, const int* in_sizes, int n_in,
                              void* d_out, int out_size, void* d_ws, size_t ws_size,
                              hipStream_t stream) {
    const float* quat  = (const float*)d_in[0];
    const float* W_in  = (const float*)d_in[1];
    const float* W_biv = (const float*)d_in[2];
    const float* b_biv = (const float*)d_in[3];
    const float* W_dec = (const float*)d_in[4];
    const float* b_dec = (const float*)d_in[5];
    const float* W_inj = (const float*)d_in[6];
    const float* b_inj = (const float*)d_in[7];
    const float* W_out = (const float*)d_in[8];
    float* out = (float*)d_out;

    float* Wc = (float*)d_ws;
    const size_t hseq_off = 32768;  // Wc uses 18432 B; keep h_seq aligned
    const size_t hseq_f32_bytes = (size_t)BB * TT * DD * sizeof(float);
    const size_t hseq_bf16_bytes = (size_t)BB * TT * DD * sizeof(__hip_bfloat16);

    precompute_wc<<<dim3(9), dim3(128), 0, stream>>>(W_in, W_biv, W_dec, W_inj, Wc);

    if (ws_size >= hseq_off + hseq_f32_bytes) {
        float* h_seq = (float*)((char*)d_ws + hseq_off);
        scan_kernel<float><<<dim3(32), dim3(64), 0, stream>>>(quat, Wc, b_biv, b_dec, b_inj, h_seq);
        out_kernel<float><<<dim3(BB * TT / 4), dim3(256), 0, stream>>>(h_seq, W_out, out);
    } else {
        // workspace too small for f32 h_seq: store bf16 (threshold is 1.9e-2, plenty of margin)
        __hip_bfloat16* h_seq = (__hip_bfloat16*)((char*)d_ws + hseq_off);
        scan_kernel<__hip_bfloat16><<<dim3(32), dim3(64), 0, stream>>>(quat, Wc, b_biv, b_dec, b_inj, h_seq);
        out_kernel<__hip_bfloat16><<<dim3(BB * TT / 4), dim3(256), 0, stream>>>(h_seq, W_out, out);
    }
}

// Round 3
// 96.748 us; speedup vs baseline: 8.0603x; 8.0603x over previous
//
#include <hip/hip_runtime.h>
#include <hip/hip_bf16.h>

#define BB 16
#define TT 2048
#define DD 384
#define GG 2048          // total chains = BB * 128
#define CC 64            // chunks over T
#define LL 32            // steps per chunk (CC*LL == TT)
#define EPSF 1e-8f

// ---------- kernel 0: combined weights Wc[m][k][j] = sum_d W_in[k][d]*Wm[d][j] ----------
// m: 0=biv, 1=dec, 2=inj.  Wc layout: [3][4][DD] row-major.
__global__ void precompute_wc(const float* __restrict__ W_in,
                              const float* __restrict__ W_biv,
                              const float* __restrict__ W_dec,
                              const float* __restrict__ W_inj,
                              float* __restrict__ Wc) {
    int idx = blockIdx.x * blockDim.x + threadIdx.x;  // 0 .. 3*DD-1
    if (idx >= 3 * DD) return;
    int m = idx / DD, j = idx - m * DD;
    const float* __restrict__ W = (m == 0) ? W_biv : (m == 1) ? W_dec : W_inj;
    float a0 = 0.f, a1 = 0.f, a2 = 0.f, a3 = 0.f;
    for (int d = 0; d < DD; ++d) {
        float wv = W[d * DD + j];
        a0 = fmaf(W_in[0 * DD + d], wv, a0);
        a1 = fmaf(W_in[1 * DD + d], wv, a1);
        a2 = fmaf(W_in[2 * DD + d], wv, a2);
        a3 = fmaf(W_in[3 * DD + d], wv, a3);
    }
    float* o = Wc + (size_t)m * 4 * DD + j;
    o[0 * DD] = a0; o[1 * DD] = a1; o[2 * DD] = a2; o[3 * DD] = a3;
}

// ---------- shared per-step math ----------
#define LOAD_CHAIN_WEIGHTS()                                        \
    const float* __restrict__ Wb = Wc;                              \
    const float* __restrict__ Wd = Wc + 4 * DD;                     \
    const float* __restrict__ Wi = Wc + 8 * DD;                     \
    float wb[4][3], wd[4][3], wi[4][3];                             \
    _Pragma("unroll")                                               \
    for (int k = 0; k < 4; ++k)                                     \
        _Pragma("unroll")                                           \
        for (int cth = 0; cth < 3; ++cth) {                         \
            wb[k][cth] = Wb[k * DD + j0 + cth];                     \
            wd[k][cth] = Wd[k * DD + j0 + cth];                     \
            wi[k][cth] = Wi[k * DD + j0 + cth];                     \
        }                                                           \
    float bbv[3], bdv[3], bjv[3];                                   \
    _Pragma("unroll")                                               \
    for (int cth = 0; cth < 3; ++cth) {                             \
        bbv[cth] = b_biv[j0 + cth];                                 \
        bdv[cth] = b_dec[j0 + cth];                                 \
        bjv[cth] = b_inj[j0 + cth];                                 \
    }

#define DOT4(W, c, bias) \
    fmaf(q.w, W[3][c], fmaf(q.z, W[2][c], fmaf(q.y, W[1][c], fmaf(q.x, W[0][c], bias))))

#define STEP_COMMON()                                               \
    float bx = DOT4(wb, 0, bbv[0]);                                 \
    float by = DOT4(wb, 1, bbv[1]);                                 \
    float bz = DOT4(wb, 2, bbv[2]);                                 \
    float d0 = DOT4(wd, 0, bdv[0]);                                 \
    float d1 = DOT4(wd, 1, bdv[1]);                                 \
    float d2 = DOT4(wd, 2, bdv[2]);                                 \
    float i0 = DOT4(wi, 0, bjv[0]);                                 \
    float i1 = DOT4(wi, 1, bjv[1]);                                 \
    float i2 = DOT4(wi, 2, bjv[2]);                                 \
    float dec0 = 1.f / (1.f + __expf(-d0));                         \
    float dec1 = 1.f / (1.f + __expf(-d1));                         \
    float dec2 = 1.f / (1.f + __expf(-d2));                         \
    float nb = fmaxf(sqrtf(fmaf(bx, bx, fmaf(by, by, bz * bz))), EPSF); \
    float half = 0.5f * nb;                                         \
    float w = __cosf(half);                                         \
    float s = __sinf(half) / nb;                                    \
    float qx = s * bz, qy = -s * by, qz = s * bx;

// ---------- kernel A: per-(chain, chunk) composed affine map ----------
// Aff layout: [CC][GG][12] = {A00,A01,A02,A10, A11,A12,A20,A21, A22,d0,d1,d2}
__global__ __launch_bounds__(128) void chunk_compose(
        const float* __restrict__ quat,
        const float* __restrict__ Wc,
        const float* __restrict__ b_biv,
        const float* __restrict__ b_dec,
        const float* __restrict__ b_inj,
        float* __restrict__ Aff) {
    int c = blockIdx.x, b = blockIdx.y, n = threadIdx.x;
    int g = b * 128 + n, j0 = 3 * n;
    LOAD_CHAIN_WEIGHTS();

    float A[3][3] = {{1.f,0.f,0.f},{0.f,1.f,0.f},{0.f,0.f,1.f}};
    float dv[3] = {0.f, 0.f, 0.f};

    const float4* __restrict__ qp4 = (const float4*)(quat + (size_t)b * TT * 4) + c * LL;

    for (int t = 0; t < LL; ++t) {
        float4 q = qp4[t];
        STEP_COMMON();
        // exact matrix form of r = v + w*t + q x t, t = 2 q x v:
        // R = I + 2w[q]x + 2(q q^T - |q|^2 I); rows scaled by dec
        float xx = qx*qx, yy = qy*qy, zz = qz*qz;
        float xy = qx*qy, xz = qx*qz, yz = qy*qz;
        float wxs = w*qx, wys = w*qy, wzs = w*qz;
        float M[3][3];
        M[0][0] = dec0 * (1.f - 2.f*(yy+zz));
        M[0][1] = dec0 * (2.f*(xy - wzs));
        M[0][2] = dec0 * (2.f*(xz + wys));
        M[1][0] = dec1 * (2.f*(xy + wzs));
        M[1][1] = dec1 * (1.f - 2.f*(xx+zz));
        M[1][2] = dec1 * (2.f*(yz - wxs));
        M[2][0] = dec2 * (2.f*(xz - wys));   // FIXED: was swapped with M[2][1]
        M[2][1] = dec2 * (2.f*(yz + wxs));   // FIXED
        M[2][2] = dec2 * (1.f - 2.f*(xx+yy));
        float nA[3][3], nd[3];
#pragma unroll
        for (int i = 0; i < 3; ++i) {
#pragma unroll
            for (int j = 0; j < 3; ++j)
                nA[i][j] = fmaf(M[i][0], A[0][j], fmaf(M[i][1], A[1][j], M[i][2] * A[2][j]));
            nd[i] = fmaf(M[i][0], dv[0], fmaf(M[i][1], dv[1], M[i][2] * dv[2]));
        }
        nd[0] += i0; nd[1] += i1; nd[2] += i2;
#pragma unroll
        for (int i = 0; i < 3; ++i) {
#pragma unroll
            for (int j = 0; j < 3; ++j) A[i][j] = nA[i][j];
            dv[i] = nd[i];
        }
    }
    float4* o = (float4*)(Aff + ((size_t)c * GG + g) * 12);
    o[0] = make_float4(A[0][0], A[0][1], A[0][2], A[1][0]);
    o[1] = make_float4(A[1][1], A[1][2], A[2][0], A[2][1]);
    o[2] = make_float4(A[2][2], dv[0], dv[1], dv[2]);
}

// ---------- kernel B: serial prefix over chunks -> per-chunk starting h ----------
// Hs layout: [CC][GG][3]
__global__ __launch_bounds__(256) void chunk_scan(
        const float* __restrict__ Aff,
        float* __restrict__ Hs) {
    int g = blockIdx.x * 256 + threadIdx.x;
    if (g >= GG) return;
    float h0 = 0.f, h1 = 0.f, h2 = 0.f;
    for (int c = 0; c < CC; ++c) {
        float* hs = Hs + ((size_t)c * GG + g) * 3;
        hs[0] = h0; hs[1] = h1; hs[2] = h2;
        const float4* a = (const float4*)(Aff + ((size_t)c * GG + g) * 12);
        float4 a0 = a[0], a1 = a[1], a2 = a[2];
        float n0 = fmaf(a0.x, h0, fmaf(a0.y, h1, fmaf(a0.z, h2, a2.y)));
        float n1 = fmaf(a0.w, h0, fmaf(a1.x, h1, fmaf(a1.y, h2, a2.z)));
        float n2 = fmaf(a1.z, h0, fmaf(a1.w, h1, fmaf(a2.x, h2, a2.w)));
        h0 = n0; h1 = n1; h2 = n2;
    }
}

// ---------- kernel C: replay chunk steps, fuse h@W_out + normalize ----------
// block = (chunk c, batch b), 128 threads = all chains of batch b
__global__ __launch_bounds__(128) void chunk_apply_out(
        const float* __restrict__ quat,
        const float* __restrict__ Wc,
        const float* __restrict__ b_biv,
        const float* __restrict__ b_dec,
        const float* __restrict__ b_inj,
        const float* __restrict__ W_out,   // [DD][4]
        const float* __restrict__ Hs,      // [CC][GG][3]
        float* __restrict__ out) {         // [BB][TT][4]
    int c = blockIdx.x, b = blockIdx.y, n = threadIdx.x;
    int g = b * 128 + n, j0 = 3 * n;
    LOAD_CHAIN_WEIGHTS();

    float wo[3][4];
#pragma unroll
    for (int r = 0; r < 3; ++r) {
        float4 wv = *(const float4*)(W_out + (size_t)(j0 + r) * 4);
        wo[r][0] = wv.x; wo[r][1] = wv.y; wo[r][2] = wv.z; wo[r][3] = wv.w;
    }

    const float* hs = Hs + ((size_t)c * GG + g) * 3;
    float vx = hs[0], vy = hs[1], vz = hs[2];

    const float4* __restrict__ qp4 = (const float4*)(quat + (size_t)b * TT * 4) + c * LL;
    float* __restrict__ outp = out + ((size_t)b * TT + (size_t)c * LL) * 4;

    __shared__ float red[2][2][4];

    for (int t = 0; t < LL; ++t) {
        float4 q = qp4[t];
        STEP_COMMON();
        // rotate v by quaternion (same form as reference)
        float tx = 2.f * (qy * vz - qz * vy);
        float ty = 2.f * (qz * vx - qx * vz);
        float tz = 2.f * (qx * vy - qy * vx);
        float rx = vx + w * tx + (qy * tz - qz * ty);
        float ry = vy + w * ty + (qz * tx - qx * tz);
        float rz = vz + w * tz + (qx * ty - qy * tx);
        vx = fmaf(dec0, rx, i0);
        vy = fmaf(dec1, ry, i1);
        vz = fmaf(dec2, rz, i2);

        // partial output row: h[j0..j0+2] . W_out rows
        float p0 = fmaf(vx, wo[0][0], fmaf(vy, wo[1][0], vz * wo[2][0]));
        float p1 = fmaf(vx, wo[0][1], fmaf(vy, wo[1][1], vz * wo[2][1]));
        float p2 = fmaf(vx, wo[0][2], fmaf(vy, wo[1][2], vz * wo[2][2]));
        float p3 = fmaf(vx, wo[0][3], fmaf(vy, wo[1][3], vz * wo[2][3]));
#pragma unroll
        for (int off = 32; off; off >>= 1) {
            p0 += __shfl_xor(p0, off);
            p1 += __shfl_xor(p1, off);
            p2 += __shfl_xor(p2, off);
            p3 += __shfl_xor(p3, off);
        }
        int wave = threadIdx.x >> 6;
        if ((threadIdx.x & 63) == 0) {
            red[t & 1][wave][0] = p0;
            red[t & 1][wave][1] = p1;
            red[t & 1][wave][2] = p2;
            red[t & 1][wave][3] = p3;
        }
        __syncthreads();
        if (threadIdx.x == 0) {
            float s0 = red[t & 1][0][0] + red[t & 1][1][0];
            float s1 = red[t & 1][0][1] + red[t & 1][1][1];
            float s2 = red[t & 1][0][2] + red[t & 1][1][2];
            float s3 = red[t & 1][0][3] + red[t & 1][1][3];
            float norm = fmaxf(sqrtf(fmaf(s0, s0, fmaf(s1, s1, fmaf(s2, s2, s3 * s3)))), EPSF);
            float inv = 1.f / norm;
            *(float4*)(outp + (size_t)t * 4) = make_float4(s0 * inv, s1 * inv, s2 * inv, s3 * inv);
        }
    }
}

extern "C" void kernel_launch(void* const* d_in, const int* in_sizes, int n_in,
                              void* d_out, int out_size, void* d_ws, size_t ws_size,
                              hipStream_t stream) {
    const float* quat  = (const float*)d_in[0];
    const float* W_in  = (const float*)d_in[1];
    const float* W_biv = (const float*)d_in[2];
    const float* b_biv = (const float*)d_in[3];
    const float* W_dec = (const float*)d_in[4];
    const float* b_dec = (const float*)d_in[5];
    const float* W_inj = (const float*)d_in[6];
    const float* b_inj = (const float*)d_in[7];
    const float* W_out = (const float*)d_in[8];
    float* out = (float*)d_out;

    float* Wc = (float*)d_ws;                                   // 3*4*DD = 4608 floats
    float* Aff = (float*)((char*)d_ws + 32768);                 // CC*GG*12 floats = 6.29 MB
    float* Hs  = (float*)((char*)d_ws + 32768 + (size_t)CC * GG * 12 * sizeof(float)); // 1.57 MB

    precompute_wc<<<dim3(9), dim3(128), 0, stream>>>(W_in, W_biv, W_dec, W_inj, Wc);
    chunk_compose<<<dim3(CC, BB), dim3(128), 0, stream>>>(quat, Wc, b_biv, b_dec, b_inj, Aff);
    chunk_scan<<<dim3(GG / 256), dim3(256), 0, stream>>>(Aff, Hs);
    chunk_apply_out<<<dim3(CC, BB), dim3(128), 0, stream>>>(quat, Wc, b_biv, b_dec, b_inj,
                                                            W_out, Hs, out);
}